// Round 2
// baseline (996.443 us; speedup 1.0000x reference)
//
#include <hip/hip_runtime.h>
#include <hip/hip_bf16.h>
#include <math.h>

// MoEHeadAdapter: N=65536, D=256, E=4, H=512, K=2, EMB=512.
// Dense-expert compute (all 4 experts scaled by sparse gates) == reference einsum.
// Dtype-agnostic: k_sniff detects fp32 vs bf16 input encoding at runtime.
// ws: [0,4) flag | [4096, +1MB) W1t [4][512][256] bf16 | +1MB W2t [4][256][512] |
//     +2MB Wpt [512][256].  Total < 2.3 MB (no large intermediates).

typedef __attribute__((ext_vector_type(4))) float f32x4;
typedef __attribute__((ext_vector_type(8))) short bf16x8;

#define MFMA16(a, b, c) __builtin_amdgcn_mfma_f32_16x16x32_bf16((a), (b), (c), 0, 0, 0)

__device__ __forceinline__ float bf2f(__hip_bfloat16 v) { return __bfloat162float(v); }

// ---------------- K-1: dtype sniff ----------------
// bf16 data: even-position ushorts are real bf16 values -> sane exponent (~100%).
// fp32 data: even-position ushorts are mantissa low bits -> sane exponent ~24%.
__global__ void k_sniff(const unsigned short* __restrict__ xr, int* __restrict__ flag) {
    int lane = threadIdx.x;
    int cnt = 0;
#pragma unroll
    for (int j = 0; j < 4; ++j) {
        unsigned short v = xr[2 * (lane * 4 + j)];
        int e = (v >> 7) & 0xFF;
        cnt += (e >= 97 && e <= 157) ? 1 : 0;
    }
#pragma unroll
    for (int off = 32; off; off >>= 1) cnt += __shfl_down(cnt, off);
    if (lane == 0) flag[0] = (cnt < 192) ? 1 : 0;  // 1 = fp32 mode
}

// ---------------- K0: weight transposes -> bf16 ----------------
__global__ void k_prep(const void* __restrict__ w1,   // [4][256][512]
                       const void* __restrict__ w2,   // [4][512][256]
                       const void* __restrict__ wp,   // [256][512]
                       const int* __restrict__ flag,
                       __hip_bfloat16* __restrict__ w1t,   // [4][512][256]
                       __hip_bfloat16* __restrict__ w2t,   // [4][256][512]
                       __hip_bfloat16* __restrict__ wpt) { // [512][256]
    int i = blockIdx.x * 256 + threadIdx.x;  // [0, 524288)
    const bool f32m = (flag[0] != 0);
    {   // w1t[e][h][d] = w1[e][d][h]
        int e = i >> 17, j = i & 131071;
        int h = j >> 8, d = j & 255;
        int s = (e << 17) + (d << 9) + h;
        w1t[i] = f32m ? __float2bfloat16(((const float*)w1)[s]) : ((const __hip_bfloat16*)w1)[s];
    }
    {   // w2t[e][d][h] = w2[e][h][d]
        int e = i >> 17, j = i & 131071;
        int d = j >> 9, h = j & 511;
        int s = (e << 17) + (h << 8) + d;
        w2t[i] = f32m ? __float2bfloat16(((const float*)w2)[s]) : ((const __hip_bfloat16*)w2)[s];
    }
    if (i < 131072) {  // wpt[n][d] = wp[d][n]
        int n = i >> 8, d = i & 255;
        int s = (d << 9) + n;
        wpt[i] = f32m ? __float2bfloat16(((const float*)wp)[s]) : ((const __hip_bfloat16*)wp)[s];
    }
}

// ---------------- fused: gating + dense expert FFN + out projection ----------------
// grid 512 x 512 threads; block = 128 tokens.
// LDS: Xs [128][264] bf16 (67584) | Hs [128][136] bf16 (34816 @67584)
//      gate_s [128][4] f32 (2048 @102400) | wgs [4][256] f32 (4096 @104448) = 108544
__global__ __launch_bounds__(512) void k_moe(
    const void* __restrict__ xin,     // [65536][256]
    const void* __restrict__ wg,      // [256][4]
    const __hip_bfloat16* __restrict__ w1t,   // [4][512][256]
    const __hip_bfloat16* __restrict__ w2t,   // [4][256][512]
    const __hip_bfloat16* __restrict__ wpt,   // [512][256]
    const void* __restrict__ bp,      // [512]
    const int* __restrict__ flag,
    void* __restrict__ outp) {        // [65536][512]
    extern __shared__ char smem[];
    __hip_bfloat16* Xs = (__hip_bfloat16*)smem;             // stride 264 (528B = 33*16, aligned)
    __hip_bfloat16* Hs = (__hip_bfloat16*)(smem + 67584);   // stride 136 (272B = 17*16)
    float* gate_s = (float*)(smem + 102400);                // [128][4]
    float* wgs = (float*)(smem + 104448);                   // [4][256]

    const int tid = threadIdx.x;
    const int m0 = blockIdx.x * 128;
    const bool f32m = (flag[0] != 0);

    // ---- stage X tile as bf16 ----
    if (!f32m) {
        const uint4* xg = (const uint4*)((const __hip_bfloat16*)xin + (size_t)m0 * 256);
#pragma unroll
        for (int i = 0; i < 8; ++i) {
            int f = tid + 512 * i;          // uint4 index over [128][32]
            int r = f >> 5, c = f & 31;
            *(uint4*)&Xs[r * 264 + c * 8] = xg[f];
        }
    } else {
        const float4* xg = (const float4*)((const float*)xin + (size_t)m0 * 256);
#pragma unroll
        for (int i = 0; i < 8; ++i) {
            int f = tid + 512 * i;
            int r = f >> 5, c = f & 31;
            float4 a = xg[2 * f], b = xg[2 * f + 1];
            __hip_bfloat16* d = &Xs[r * 264 + c * 8];
            d[0] = __float2bfloat16(a.x); d[1] = __float2bfloat16(a.y);
            d[2] = __float2bfloat16(a.z); d[3] = __float2bfloat16(a.w);
            d[4] = __float2bfloat16(b.x); d[5] = __float2bfloat16(b.y);
            d[6] = __float2bfloat16(b.z); d[7] = __float2bfloat16(b.w);
        }
    }
    if (tid < 256) {  // w_gate transposed to LDS as f32: wgs[e][d]
#pragma unroll
        for (int e = 0; e < 4; ++e)
            wgs[e * 256 + tid] = f32m ? ((const float*)wg)[tid * 4 + e]
                                      : bf2f(((const __hip_bfloat16*)wg)[tid * 4 + e]);
    }
    __syncthreads();

    // ---- gating logits at FULL input precision (top-k is discrete!) ----
    {
        int tok = tid >> 2, e = tid & 3;
        float acc = 0.f;
        if (f32m) {
            const float4* xrow = (const float4*)((const float*)xin + (size_t)(m0 + tok) * 256);
            const float* wrow = &wgs[e * 256];
#pragma unroll 8
            for (int q = 0; q < 64; ++q) {
                float4 xv = xrow[q];
                acc += xv.x * wrow[q * 4] + xv.y * wrow[q * 4 + 1]
                     + xv.z * wrow[q * 4 + 2] + xv.w * wrow[q * 4 + 3];
            }
        } else {
            const float* wrow = &wgs[e * 256];
#pragma unroll 4
            for (int d8 = 0; d8 < 32; ++d8) {
                bf16x8 xv = *(const bf16x8*)&Xs[tok * 264 + d8 * 8];
#pragma unroll
                for (int j = 0; j < 8; ++j) {
                    union { unsigned u; float f; } c;
                    c.u = ((unsigned)(unsigned short)xv[j]) << 16;
                    acc += c.f * wrow[d8 * 8 + j];
                }
            }
        }
        gate_s[tok * 4 + e] = acc;  // logits for now
    }
    __syncthreads();
    // top-2 + softmax (jax.lax.top_k ties -> lowest index; strict > keeps first)
    if (tid < 128) {
        float l[4];
#pragma unroll
        for (int e = 0; e < 4; ++e) l[e] = gate_s[tid * 4 + e];
        int i0 = 0; float v0 = l[0];
#pragma unroll
        for (int e = 1; e < 4; ++e)
            if (l[e] > v0) { v0 = l[e]; i0 = e; }
        int i1 = -1; float v1 = -1e30f;
#pragma unroll
        for (int e = 0; e < 4; ++e)
            if (e != i0 && l[e] > v1) { v1 = l[e]; i1 = e; }
        float t = expf(v1 - v0);
        float g0 = 1.f / (1.f + t);
        float g1 = t * g0;
#pragma unroll
        for (int e = 0; e < 4; ++e) gate_s[tid * 4 + e] = 0.f;
        gate_s[tid * 4 + i0] = g0;
        gate_s[tid * 4 + i1] = g1;
    }
    __syncthreads();

    const int lane = tid & 63;
    const int wv = tid >> 6;       // 8 waves
    const int wr = wv & 3;         // rows 32*wr..+32
    const int wc = wv >> 2;        // col group 0/1
    const int lm = lane & 15, quad = lane >> 4;

    f32x4 Yacc[2][8];  // Y wave-tile [32][128]
#pragma unroll
    for (int a = 0; a < 2; ++a)
#pragma unroll
        for (int b = 0; b < 8; ++b) Yacc[a][b] = (f32x4){0.f, 0.f, 0.f, 0.f};

#pragma unroll 1
    for (int e = 0; e < 4; ++e) {
        const __hip_bfloat16* w1e = w1t + (e << 17);
        const __hip_bfloat16* w2e = w2t + (e << 17);
#pragma unroll 1
        for (int hc = 0; hc < 512; hc += 128) {
            // Phase A: Hc[128][128] = X @ W1e[:, hc:hc+128]; wave sub-tile [32][64]
            f32x4 Hacc[2][4];
#pragma unroll
            for (int a = 0; a < 2; ++a)
#pragma unroll
                for (int b = 0; b < 4; ++b) Hacc[a][b] = (f32x4){0.f, 0.f, 0.f, 0.f};
#pragma unroll
            for (int k = 0; k < 256; k += 32) {
                bf16x8 af[2];
#pragma unroll
                for (int mt = 0; mt < 2; ++mt)
                    af[mt] = *(const bf16x8*)&Xs[(32 * wr + 16 * mt + lm) * 264 + k + quad * 8];
#pragma unroll
                for (int nt = 0; nt < 4; ++nt) {
                    int h = hc + 64 * wc + 16 * nt + lm;
                    bf16x8 bfr = *(const bf16x8*)&w1e[(h << 8) + k + quad * 8];
                    Hacc[0][nt] = MFMA16(af[0], bfr, Hacc[0][nt]);
                    Hacc[1][nt] = MFMA16(af[1], bfr, Hacc[1][nt]);
                }
            }
            // exact gelu + gate scale -> Hs (bf16)
#pragma unroll
            for (int mt = 0; mt < 2; ++mt)
#pragma unroll
                for (int nt = 0; nt < 4; ++nt)
#pragma unroll
                    for (int r = 0; r < 4; ++r) {
                        int row = 32 * wr + 16 * mt + quad * 4 + r;
                        int col = 64 * wc + 16 * nt + lm;
                        float v = Hacc[mt][nt][r];
                        float g = 0.5f * v * (1.f + erff(v * 0.70710678118654752f));
                        g *= gate_s[row * 4 + e];
                        Hs[row * 136 + col] = __float2bfloat16(g);
                    }
            __syncthreads();
            // Phase B: Y += Hc @ W2e[hc:hc+128, :]
#pragma unroll
            for (int kk = 0; kk < 128; kk += 32) {
                bf16x8 af[2];
#pragma unroll
                for (int mt = 0; mt < 2; ++mt)
                    af[mt] = *(const bf16x8*)&Hs[(32 * wr + 16 * mt + lm) * 136 + kk + quad * 8];
#pragma unroll
                for (int nt = 0; nt < 8; ++nt) {
                    int d = 128 * wc + 16 * nt + lm;
                    bf16x8 bfr = *(const bf16x8*)&w2e[(d << 9) + hc + kk + quad * 8];
                    Yacc[0][nt] = MFMA16(af[0], bfr, Yacc[0][nt]);
                    Yacc[1][nt] = MFMA16(af[1], bfr, Yacc[1][nt]);
                }
            }
            __syncthreads();
        }
    }

    // ---- Y -> LDS (reuse Xs region; all waves past their last Xs read) ----
#pragma unroll
    for (int mt = 0; mt < 2; ++mt)
#pragma unroll
        for (int nt = 0; nt < 8; ++nt)
#pragma unroll
            for (int r = 0; r < 4; ++r) {
                int row = 32 * wr + 16 * mt + quad * 4 + r;
                int col = 128 * wc + 16 * nt + lm;
                Xs[row * 264 + col] = __float2bfloat16(Yacc[mt][nt][r]);
            }
    __syncthreads();

    // ---- projection: OUT[128][512] = Y @ Wproj + b ----
#pragma unroll 1
    for (int p = 0; p < 2; ++p) {
        int n0 = 128 * (2 * wc + p);
        f32x4 acc[2][8];
#pragma unroll
        for (int a = 0; a < 2; ++a)
#pragma unroll
            for (int b = 0; b < 8; ++b) acc[a][b] = (f32x4){0.f, 0.f, 0.f, 0.f};
#pragma unroll
        for (int k = 0; k < 256; k += 32) {
            bf16x8 af[2];
#pragma unroll
            for (int mt = 0; mt < 2; ++mt)
                af[mt] = *(const bf16x8*)&Xs[(32 * wr + 16 * mt + lm) * 264 + k + quad * 8];
#pragma unroll
            for (int nt = 0; nt < 8; ++nt) {
                int n = n0 + 16 * nt + lm;
                bf16x8 bfr = *(const bf16x8*)&wpt[(n << 8) + k + quad * 8];
                acc[0][nt] = MFMA16(af[0], bfr, acc[0][nt]);
                acc[1][nt] = MFMA16(af[1], bfr, acc[1][nt]);
            }
        }
#pragma unroll
        for (int nt = 0; nt < 8; ++nt) {
            int col = n0 + 16 * nt + lm;
            float bv = f32m ? ((const float*)bp)[col] : bf2f(((const __hip_bfloat16*)bp)[col]);
#pragma unroll
            for (int mt = 0; mt < 2; ++mt)
#pragma unroll
                for (int r = 0; r < 4; ++r) {
                    int row = m0 + 32 * wr + 16 * mt + quad * 4 + r;
                    float v = acc[mt][nt][r] + bv;
                    if (f32m) ((float*)outp)[(size_t)row * 512 + col] = v;
                    else ((__hip_bfloat16*)outp)[(size_t)row * 512 + col] = __float2bfloat16(v);
                }
        }
    }
}

extern "C" void kernel_launch(void* const* d_in, const int* in_sizes, int n_in,
                              void* d_out, int out_size, void* d_ws, size_t ws_size,
                              hipStream_t stream) {
    const void* x  = d_in[0];
    const void* wg = d_in[1];
    const void* w1 = d_in[2];
    const void* w2 = d_in[3];
    const void* wp = d_in[4];
    const void* bp = d_in[5];

    char* ws = (char*)d_ws;
    int* flag = (int*)(ws + 0);
    __hip_bfloat16* w1t = (__hip_bfloat16*)(ws + 4096);
    __hip_bfloat16* w2t = (__hip_bfloat16*)(ws + 4096 + (1u << 20));
    __hip_bfloat16* wpt = (__hip_bfloat16*)(ws + 4096 + (2u << 20));

    k_sniff<<<1, 64, 0, stream>>>((const unsigned short*)x, flag);
    k_prep<<<2048, 256, 0, stream>>>(w1, w2, wp, flag, w1t, w2t, wpt);
    k_moe<<<512, 512, 108544, stream>>>(x, wg, w1t, w2t, wpt, bp, flag, d_out);
}